// Round 3
// baseline (187.508 us; speedup 1.0000x reference)
//
#include <hip/hip_runtime.h>
#include <hip/hip_bf16.h>

// Problem constants
#define B_  128
#define I_  64
#define P_  16
#define T_  5
#define NT  3
#define VOCAB 100000
#define D_  64
#define NROWS (NT * VOCAB)     // 300000
#define NPAIR (B_ * I_)        // 8192 (n)
#define OUTROWS NPAIR          // 8192 output rows of 64

// ---------- bf16 helpers ----------
__device__ __forceinline__ float b2f(unsigned short h) {
    return __uint_as_float(((unsigned int)h) << 16);
}
__device__ __forceinline__ unsigned short f2b(float f) {
    unsigned int u = __float_as_uint(f);
    return (unsigned short)((u + 0x7fffu + ((u >> 16) & 1u)) >> 16);   // RNE
}

typedef short short8 __attribute__((ext_vector_type(8)));
typedef float f32x4 __attribute__((ext_vector_type(4)));

// =====================================================================
// Phase 1: UV[r][c] for c<64: U = T[r,:]·W0[c,:] ; c>=64: V = T[r,:]·W1[c-64,:]
// Weights as FIRST mfma operand so D-rows = channels (8B stores).
// Each wave owns 4 tiles (64 rows); ALL 16 A float4 loads issued upfront
// for memory-level parallelism (the R1 bottleneck: ~450B in flight/CU).
// =====================================================================
#define LDB 72   // padded row stride for weight tile (bf16 elems)
__global__ __launch_bounds__(256, 4) void transform_tables(
        const float* __restrict__ tables, const float* __restrict__ convw,
        unsigned short* __restrict__ UV) {
    // 32 KB LDS: fp32 convw staging, then reused (aliased) as bf16 Bt tile.
    __shared__ __align__(16) char smem[32768];
    float* wraw = (float*)smem;                 // 8192 floats
    unsigned short* Bt = (unsigned short*)smem; // 128*LDB = 9216 shorts (18432 B)

    const int tid = threadIdx.x;
    // 1) coalesced load of convw into LDS
    {
        float4* dst = (float4*)wraw;
        const float4* src = (const float4*)convw;
        for (int i = tid; i < 2048; i += 256) dst[i] = src[i];
    }
    __syncthreads();
    // 2) gather my 32 Bt entries into regs (reads wraw)
    unsigned short breg[32];
#pragma unroll
    for (int j = 0; j < 32; ++j) {
        int i = tid * 32 + j;
        int c = i >> 6, col = i & 63;
        float v = (c < 64) ? wraw[c * 128 + col * 2]
                           : wraw[(c - 64) * 128 + col * 2 + 1];
        breg[j] = f2b(v);
    }
    __syncthreads();
    // 3) write Bt (now safe to overwrite wraw)
#pragma unroll
    for (int j = 0; j < 32; ++j) {
        int i = tid * 32 + j;
        int c = i >> 6, col = i & 63;
        Bt[c * LDB + col] = breg[j];
    }
    __syncthreads();

    const int w = tid >> 6;          // wave 0..3
    const int lane = tid & 63;
    const int l16 = lane & 15;
    const int quad = lane >> 4;
    const int base_tile = blockIdx.x * 16 + w * 4;   // 4 consecutive tiles/wave

    // ---- issue ALL 16 A loads upfront (4 tiles x 4 float4) ----
    float4 A[16];
#pragma unroll
    for (int t = 0; t < 4; ++t) {
        int row = (base_tile + t) * 16 + l16;
        int rowc = row < NROWS ? row : NROWS - 1;
        const float* ap = tables + (size_t)rowc * 64 + quad * 8;
        A[t * 4 + 0] = *(const float4*)(ap);
        A[t * 4 + 1] = *(const float4*)(ap + 4);
        A[t * 4 + 2] = *(const float4*)(ap + 32);
        A[t * 4 + 3] = *(const float4*)(ap + 36);
    }

#pragma unroll
    for (int t = 0; t < 4; ++t) {
        float4 fa = A[t * 4 + 0], fb = A[t * 4 + 1];
        float4 fc = A[t * 4 + 2], fd = A[t * 4 + 3];
        short8 a0, a1;
        a0[0] = (short)f2b(fa.x); a0[1] = (short)f2b(fa.y);
        a0[2] = (short)f2b(fa.z); a0[3] = (short)f2b(fa.w);
        a0[4] = (short)f2b(fb.x); a0[5] = (short)f2b(fb.y);
        a0[6] = (short)f2b(fb.z); a0[7] = (short)f2b(fb.w);
        a1[0] = (short)f2b(fc.x); a1[1] = (short)f2b(fc.y);
        a1[2] = (short)f2b(fc.z); a1[3] = (short)f2b(fc.w);
        a1[4] = (short)f2b(fd.x); a1[5] = (short)f2b(fd.y);
        a1[6] = (short)f2b(fd.z); a1[7] = (short)f2b(fd.w);

        f32x4 acc[8];
#pragma unroll
        for (int ns = 0; ns < 8; ++ns) acc[ns] = (f32x4){0.f, 0.f, 0.f, 0.f};
#pragma unroll
        for (int ns = 0; ns < 8; ++ns) {
            short8 b0 = *(const short8*)&Bt[(ns * 16 + l16) * LDB + quad * 8];
            short8 b1 = *(const short8*)&Bt[(ns * 16 + l16) * LDB + 32 + quad * 8];
            acc[ns] = __builtin_amdgcn_mfma_f32_16x16x32_bf16(b0, a0, acc[ns], 0, 0, 0);
            acc[ns] = __builtin_amdgcn_mfma_f32_16x16x32_bf16(b1, a1, acc[ns], 0, 0, 0);
        }
        // D layout: col(lane&15)=table row, row(quad*4+j)=channel -> 8B stores
        int row = (base_tile + t) * 16 + l16;
        if (row < NROWS) {
            unsigned short* op = UV + (size_t)row * 128 + quad * 4;
#pragma unroll
            for (int ns = 0; ns < 8; ++ns) {
                unsigned long long pk =
                      (unsigned long long)f2b(acc[ns][0])
                    | ((unsigned long long)f2b(acc[ns][1]) << 16)
                    | ((unsigned long long)f2b(acc[ns][2]) << 32)
                    | ((unsigned long long)f2b(acc[ns][3]) << 48);
                *(unsigned long long*)(op + ns * 16) = pk;
            }
        }
    }
}

// =====================================================================
// Phase 2: final[nn,d] = b[d] + max_{pp,to} ( U[r_to,d] + V[r_{t+1},d] )
//   m = pp*512 + (nn>>4), q = nn&15, r_t = type[t]*VOCAB + x[m,q,t]
// 256-thr blocks (4 nn), indices staged in LDS, pp unrolled 8 for MLP.
// =====================================================================
__global__ __launch_bounds__(256, 4) void gather_max(
        const int* __restrict__ path_input, const int* __restrict__ path_type,
        const unsigned short* __restrict__ UV, const float* __restrict__ bias,
        float* __restrict__ out) {
    __shared__ int ridx[4][16][5];
    const int tid = threadIdx.x;
    const int nn0 = blockIdx.x * 4;
    for (int i = tid; i < 320; i += 256) {
        int ln = i / 80, j = i - ln * 80;
        int pp = j / 5, t = j - pp * 5;
        int nn = nn0 + ln;
        int g = nn >> 4, q = nn & 15;
        int addr = ((pp * 512 + g) * 16 + q) * 5 + t;
        ridx[ln][pp][t] = (path_type[t] * VOCAB + path_input[addr]) * 128;
    }
    __syncthreads();

    const int w = tid >> 6, d = tid & 63;
    const int nn = nn0 + w;
    float acc = -1e30f;
#pragma unroll 8
    for (int pp = 0; pp < 16; ++pp) {
        int r0 = ridx[w][pp][0];
        int r1 = ridx[w][pp][1];
        int r2 = ridx[w][pp][2];
        int r3 = ridx[w][pp][3];
        int r4 = ridx[w][pp][4];
        float u0 = b2f(UV[r0 + d]);
        float u1 = b2f(UV[r1 + d]);
        float u2 = b2f(UV[r2 + d]);
        float u3 = b2f(UV[r3 + d]);
        float v1 = b2f(UV[r1 + 64 + d]);
        float v2 = b2f(UV[r2 + 64 + d]);
        float v3 = b2f(UV[r3 + 64 + d]);
        float v4 = b2f(UV[r4 + 64 + d]);
        acc = fmaxf(acc, u0 + v1);
        acc = fmaxf(acc, u1 + v2);
        acc = fmaxf(acc, u2 + v3);
        acc = fmaxf(acc, u3 + v4);
    }
    out[(size_t)nn * 64 + d] = acc + bias[d];
}

// =====================================================================
// Fallback (if workspace too small): direct fused fp32.
// =====================================================================
__global__ __launch_bounds__(64) void fused_direct(
        const int* __restrict__ path_input, const int* __restrict__ path_type,
        const float* __restrict__ tables, const float* __restrict__ convw,
        const float* __restrict__ bias, float* __restrict__ out) {
    const int nn = blockIdx.x;
    const int o = threadIdx.x;
    const int g = nn >> 4;
    const int q = nn & 15;
    float w0[64], w1[64];
#pragma unroll
    for (int i = 0; i < 64; ++i) {
        w0[i] = convw[o * 128 + i * 2];
        w1[i] = convw[o * 128 + i * 2 + 1];
    }
    int tb[5];
#pragma unroll
    for (int t = 0; t < 5; ++t) tb[t] = path_type[t] * VOCAB;
    __shared__ float emb[5][64];
    float acc = -1e30f;
    for (int pp = 0; pp < 16; ++pp) {
        int m = pp * 512 + g;
        const int* ip = path_input + ((m * 16 + q) * 5);
        __syncthreads();
#pragma unroll
        for (int t = 0; t < 5; ++t)
            emb[t][o] = tables[(size_t)(tb[t] + ip[t]) * 64 + o];
        __syncthreads();
#pragma unroll
        for (int to = 0; to < 4; ++to) {
            float s = 0.f;
#pragma unroll
            for (int i = 0; i < 64; ++i)
                s += w0[i] * emb[to][i] + w1[i] * emb[to + 1][i];
            acc = fmaxf(acc, s);
        }
    }
    out[(size_t)nn * 64 + o] = acc + bias[o];
}

extern "C" void kernel_launch(void* const* d_in, const int* in_sizes, int n_in,
                              void* d_out, int out_size, void* d_ws, size_t ws_size,
                              hipStream_t stream) {
    const int*   path_input = (const int*)d_in[0];
    const int*   path_type  = (const int*)d_in[1];
    const float* tables     = (const float*)d_in[2];
    const float* convw      = (const float*)d_in[3];
    const float* convb      = (const float*)d_in[4];
    float* out = (float*)d_out;

    const size_t need = (size_t)NROWS * 128 * sizeof(unsigned short); // 76.8 MB
    if (ws_size >= need) {
        unsigned short* UV = (unsigned short*)d_ws;
        // 1172 blocks x 16 tiles = 18752 tiles >= 18750
        transform_tables<<<1172, 256, 0, stream>>>(tables, convw, UV);
        gather_max<<<OUTROWS / 4, 256, 0, stream>>>(path_input, path_type, UV, convb, out);
    } else {
        fused_direct<<<OUTROWS, 64, 0, stream>>>(path_input, path_type, tables, convw, convb, out);
    }
}

// Round 4
// 171.496 us; speedup vs baseline: 1.0934x; 1.0934x over previous
//
#include <hip/hip_runtime.h>
#include <hip/hip_bf16.h>

// Problem constants
#define B_  128
#define I_  64
#define P_  16
#define T_  5
#define NT  3
#define VOCAB 100000
#define D_  64
#define NROWS (NT * VOCAB)     // 300000
#define NPAIR (B_ * I_)        // 8192 (n)
#define OUTROWS NPAIR          // 8192 output rows of 64

// ---------- bf16 helpers ----------
__device__ __forceinline__ float b2f(unsigned short h) {
    return __uint_as_float(((unsigned int)h) << 16);
}
__device__ __forceinline__ unsigned short f2b(float f) {
    unsigned int u = __float_as_uint(f);
    return (unsigned short)((u + 0x7fffu + ((u >> 16) & 1u)) >> 16);   // RNE
}
__device__ __forceinline__ float pkLo(unsigned int x) {      // low bf16 -> f32
    return __uint_as_float(x << 16);
}
__device__ __forceinline__ float pkHi(unsigned int x) {      // high bf16 -> f32
    return __uint_as_float(x & 0xffff0000u);
}

typedef short short8 __attribute__((ext_vector_type(8)));
typedef float f32x4 __attribute__((ext_vector_type(4)));

// =====================================================================
// Phase 1: UV[r][c] for c<64: U = T[r,:]·W0[c,:] ; c>=64: V = T[r,:]·W1[c-64,:]
// Weights as FIRST mfma operand so D-rows = channels (8B stores).
// Each wave owns 4 tiles; all 16 A float4 loads issued upfront for MLP.
// NO min-waves launch bound: R2 showed a 64-VGPR cap spills A[16] to
// scratch (+57MB write traffic). Let VGPR float to ~160, 2-3 waves/SIMD.
// =====================================================================
#define LDB 72   // padded row stride for weight tile (bf16 elems)
__global__ __launch_bounds__(256) void transform_tables(
        const float* __restrict__ tables, const float* __restrict__ convw,
        unsigned short* __restrict__ UV) {
    __shared__ unsigned short Bt[128 * LDB];   // 18432 B
    const int tid = threadIdx.x;

    // Bt[c][i]: c<64 -> W[c][i][0], c>=64 -> W[c-64][i][1]; convw[o*128+i*2+k]
    {
        int c = tid >> 1, half = tid & 1;
        const float* wp = (c < 64) ? (convw + c * 128) : (convw + (c - 64) * 128 + 1);
#pragma unroll
        for (int k = 0; k < 32; ++k) {
            int i = half * 32 + k;
            Bt[c * LDB + i] = f2b(wp[i * 2]);
        }
    }
    __syncthreads();

    const int w = tid >> 6;          // wave 0..3
    const int lane = tid & 63;
    const int l16 = lane & 15;
    const int quad = lane >> 4;
    const int base_tile = blockIdx.x * 16 + w * 4;

    // ---- issue ALL 16 A loads upfront (4 tiles x 4 float4) ----
    float4 A[16];
#pragma unroll
    for (int t = 0; t < 4; ++t) {
        int row = (base_tile + t) * 16 + l16;
        int rowc = row < NROWS ? row : NROWS - 1;
        const float* ap = tables + (size_t)rowc * 64 + quad * 8;
        A[t * 4 + 0] = *(const float4*)(ap);
        A[t * 4 + 1] = *(const float4*)(ap + 4);
        A[t * 4 + 2] = *(const float4*)(ap + 32);
        A[t * 4 + 3] = *(const float4*)(ap + 36);
    }

#pragma unroll
    for (int t = 0; t < 4; ++t) {
        float4 fa = A[t * 4 + 0], fb = A[t * 4 + 1];
        float4 fc = A[t * 4 + 2], fd = A[t * 4 + 3];
        short8 a0, a1;
        a0[0] = (short)f2b(fa.x); a0[1] = (short)f2b(fa.y);
        a0[2] = (short)f2b(fa.z); a0[3] = (short)f2b(fa.w);
        a0[4] = (short)f2b(fb.x); a0[5] = (short)f2b(fb.y);
        a0[6] = (short)f2b(fb.z); a0[7] = (short)f2b(fb.w);
        a1[0] = (short)f2b(fc.x); a1[1] = (short)f2b(fc.y);
        a1[2] = (short)f2b(fc.z); a1[3] = (short)f2b(fc.w);
        a1[4] = (short)f2b(fd.x); a1[5] = (short)f2b(fd.y);
        a1[6] = (short)f2b(fd.z); a1[7] = (short)f2b(fd.w);

        f32x4 acc[8];
#pragma unroll
        for (int ns = 0; ns < 8; ++ns) acc[ns] = (f32x4){0.f, 0.f, 0.f, 0.f};
#pragma unroll
        for (int ns = 0; ns < 8; ++ns) {
            short8 b0 = *(const short8*)&Bt[(ns * 16 + l16) * LDB + quad * 8];
            short8 b1 = *(const short8*)&Bt[(ns * 16 + l16) * LDB + 32 + quad * 8];
            acc[ns] = __builtin_amdgcn_mfma_f32_16x16x32_bf16(b0, a0, acc[ns], 0, 0, 0);
            acc[ns] = __builtin_amdgcn_mfma_f32_16x16x32_bf16(b1, a1, acc[ns], 0, 0, 0);
        }
        // D layout: col(lane&15)=table row, row(quad*4+j)=channel -> 8B stores
        int row = (base_tile + t) * 16 + l16;
        if (row < NROWS) {
            unsigned short* op = UV + (size_t)row * 128 + quad * 4;
#pragma unroll
            for (int ns = 0; ns < 8; ++ns) {
                unsigned long long pk =
                      (unsigned long long)f2b(acc[ns][0])
                    | ((unsigned long long)f2b(acc[ns][1]) << 16)
                    | ((unsigned long long)f2b(acc[ns][2]) << 32)
                    | ((unsigned long long)f2b(acc[ns][3]) << 48);
                *(unsigned long long*)(op + ns * 16) = pk;
            }
        }
    }
}

// =====================================================================
// Phase 2: final[nn,d] = b[d] + max_{pp,to} ( U[r_to,d] + V[r_{t+1},d] )
// Paired-gather scheme: one dword load serves TWO row-gathers (lanes
// 0-31 = gather A channels as bf16x2, lanes 32-63 = gather B). Window
// terms align across halves: half0 accumulates u0+v1, u2+v3; half1
// accumulates u1+v2, u3+v4; one shfl_xor(32)+max merges. 4 VMEM/pp
// instead of 8, ~half the VGPRs per unroll step.
// =====================================================================
__global__ __launch_bounds__(256) void gather_max(
        const int* __restrict__ path_input, const int* __restrict__ path_type,
        const unsigned int* __restrict__ UVu, const float* __restrict__ bias,
        float* __restrict__ out) {
    __shared__ int ridx[4][16][5];   // row * 64 (uint offsets)
    const int tid = threadIdx.x;
    const int nn0 = blockIdx.x * 4;
    for (int i = tid; i < 320; i += 256) {
        int ln = i / 80, j = i - ln * 80;
        int pp = j / 5, t = j - pp * 5;
        int nn = nn0 + ln;
        int g = nn >> 4, q = nn & 15;
        int addr = ((pp * 512 + g) * 16 + q) * 5 + t;
        ridx[ln][pp][t] = (path_type[t] * VOCAB + path_input[addr]) * 64;
    }
    __syncthreads();

    const int w = tid >> 6, lane = tid & 63;
    const int half = lane >> 5, l = lane & 31;
    const int nn = nn0 + w;

    float accLo = -1e30f, accHi = -1e30f;
#pragma unroll 8
    for (int pp = 0; pp < 16; ++pp) {
        int r0 = ridx[w][pp][0];
        int r1 = ridx[w][pp][1];
        int r2 = ridx[w][pp][2];
        int r3 = ridx[w][pp][3];
        int r4 = ridx[w][pp][4];
        // U-half of row r: uints [r .. r+31]; V-half: [r+32 .. r+63]
        unsigned int xa = UVu[(half ? r1 : r0) + l];          // {u0 | u1}
        unsigned int xb = UVu[(half ? r3 : r2) + l];          // {u2 | u3}
        unsigned int xc = UVu[(half ? r2 : r1) + 32 + l];     // {v1 | v2}
        unsigned int xd = UVu[(half ? r4 : r3) + 32 + l];     // {v3 | v4}
        float s1Lo = pkLo(xa) + pkLo(xc);   // u+v, even channel
        float s1Hi = pkHi(xa) + pkHi(xc);   // odd channel
        float s2Lo = pkLo(xb) + pkLo(xd);
        float s2Hi = pkHi(xb) + pkHi(xd);
        accLo = fmaxf(accLo, fmaxf(s1Lo, s2Lo));
        accHi = fmaxf(accHi, fmaxf(s1Hi, s2Hi));
    }
    // merge the two halves' window terms
    float oLo = fmaxf(accLo, __shfl_xor(accLo, 32));
    float oHi = fmaxf(accHi, __shfl_xor(accHi, 32));
    if (half == 0) {
        float2 bv = *(const float2*)(bias + 2 * l);
        float2 o;
        o.x = oLo + bv.x;
        o.y = oHi + bv.y;
        *(float2*)(out + (size_t)nn * 64 + 2 * l) = o;
    }
}

// =====================================================================
// Fallback (if workspace too small): direct fused fp32.
// =====================================================================
__global__ __launch_bounds__(64) void fused_direct(
        const int* __restrict__ path_input, const int* __restrict__ path_type,
        const float* __restrict__ tables, const float* __restrict__ convw,
        const float* __restrict__ bias, float* __restrict__ out) {
    const int nn = blockIdx.x;
    const int o = threadIdx.x;
    const int g = nn >> 4;
    const int q = nn & 15;
    float w0[64], w1[64];
#pragma unroll
    for (int i = 0; i < 64; ++i) {
        w0[i] = convw[o * 128 + i * 2];
        w1[i] = convw[o * 128 + i * 2 + 1];
    }
    int tb[5];
#pragma unroll
    for (int t = 0; t < 5; ++t) tb[t] = path_type[t] * VOCAB;
    __shared__ float emb[5][64];
    float acc = -1e30f;
    for (int pp = 0; pp < 16; ++pp) {
        int m = pp * 512 + g;
        const int* ip = path_input + ((m * 16 + q) * 5);
        __syncthreads();
#pragma unroll
        for (int t = 0; t < 5; ++t)
            emb[t][o] = tables[(size_t)(tb[t] + ip[t]) * 64 + o];
        __syncthreads();
#pragma unroll
        for (int to = 0; to < 4; ++to) {
            float s = 0.f;
#pragma unroll
            for (int i = 0; i < 64; ++i)
                s += w0[i] * emb[to][i] + w1[i] * emb[to + 1][i];
            acc = fmaxf(acc, s);
        }
    }
    out[(size_t)nn * 64 + o] = acc + bias[o];
}

extern "C" void kernel_launch(void* const* d_in, const int* in_sizes, int n_in,
                              void* d_out, int out_size, void* d_ws, size_t ws_size,
                              hipStream_t stream) {
    const int*   path_input = (const int*)d_in[0];
    const int*   path_type  = (const int*)d_in[1];
    const float* tables     = (const float*)d_in[2];
    const float* convw      = (const float*)d_in[3];
    const float* convb      = (const float*)d_in[4];
    float* out = (float*)d_out;

    const size_t need = (size_t)NROWS * 128 * sizeof(unsigned short); // 76.8 MB
    if (ws_size >= need) {
        unsigned short* UV = (unsigned short*)d_ws;
        // 1172 blocks x 16 tiles = 18752 tiles >= 18750
        transform_tables<<<1172, 256, 0, stream>>>(tables, convw, UV);
        gather_max<<<OUTROWS / 4, 256, 0, stream>>>(path_input, path_type,
                                                    (const unsigned int*)UV, convb, out);
    } else {
        fused_direct<<<OUTROWS, 64, 0, stream>>>(path_input, path_type, tables, convw, convb, out);
    }
}